// Round 1
// baseline (264.341 us; speedup 1.0000x reference)
//
#include <hip/hip_runtime.h>
#include <math.h>

// Problem constants (from reference): T=512, E=64, H=2*E=128, b=2 (derived
// from out_size at launch, so no hardcoded batch).
#define TT 512
#define EE 64
#define HH 128

// Kernel 1: rows[d][h] = (gelu_exact(pos[d] @ W1 + b1) @ W2 + b2)[h]
// One block per distance d (512 blocks), 128 threads (one per output column h).
__global__ void rows_kernel(const float* __restrict__ pos,
                            const float* __restrict__ W1,
                            const float* __restrict__ b1,
                            const float* __restrict__ W2,
                            const float* __restrict__ b2,
                            float* __restrict__ rows) {
    const int d = blockIdx.x;
    const int t = threadIdx.x;   // 0..127

    __shared__ float p[EE];   // pos_table row d
    __shared__ float h[HH];   // hidden activations

    if (t < EE) p[t] = pos[d * EE + t];
    __syncthreads();

    // h[t] = gelu(pos[d] . W1[:,t] + b1[t]), exact gelu (erf form)
    float acc = b1[t];
#pragma unroll
    for (int e = 0; e < EE; ++e) acc += p[e] * W1[e * HH + t];
    h[t] = 0.5f * acc * (1.0f + erff(acc * 0.7071067811865475f));
    __syncthreads();

    // rows[d][t] = h . W2[:,t] + b2[t]
    float acc2 = b2[t];
#pragma unroll
    for (int k = 0; k < HH; ++k) acc2 += h[k] * W2[k * HH + t];
    rows[d * HH + t] = acc2;
}

// Kernel 2: out[b][i][j][:] = rows[max(i-j,0)][:]
// One thread per output float4. Row = HH floats = 32 float4.
// Consecutive lanes: same row reads are consecutive float4 (coalesced, L2-hot),
// writes are fully coalesced 16B/lane.
__global__ void scatter_kernel(const float4* __restrict__ rows4,
                               float4* __restrict__ out4) {
    const long idx = (long)blockIdx.x * blockDim.x + threadIdx.x;
    const int  q = (int)(idx & 31);          // float4 index within row (HH/4=32)
    const long r = idx >> 5;                 // flat (b,i,j) row index
    const int  j = (int)(r & (TT - 1));
    const int  i = (int)((r >> 9) & (TT - 1));
    const int  d = (i >= j) ? (i - j) : 0;   // tril(i-j)
    out4[idx] = rows4[d * (HH / 4) + q];
}

extern "C" void kernel_launch(void* const* d_in, const int* in_sizes, int n_in,
                              void* d_out, int out_size, void* d_ws, size_t ws_size,
                              hipStream_t stream) {
    // setup_inputs order: b(int scalar), pos_table, W1, b1, W2, b2 — all fp32
    const float* pos = (const float*)d_in[1];
    const float* W1  = (const float*)d_in[2];
    const float* b1  = (const float*)d_in[3];
    const float* W2  = (const float*)d_in[4];
    const float* b2  = (const float*)d_in[5];
    float* out  = (float*)d_out;
    float* rows = (float*)d_ws;              // TT*HH*4 = 256 KB scratch

    rows_kernel<<<TT, HH, 0, stream>>>(pos, W1, b1, W2, b2, rows);

    const long total4 = (long)out_size / 4;  // out_size = b*TT*TT*HH
    const int  block  = 256;
    const long grid   = (total4 + block - 1) / block;
    scatter_kernel<<<dim3((unsigned)grid), dim3(block), 0, stream>>>(
        (const float4*)rows, (float4*)out);
}